// Round 11
// baseline (17.673 us; speedup 1.0000x reference)
//
#include <hip/hip_runtime.h>
#include <math.h>

#define N_PTS  1000000
#define M_COMP 64

typedef float v2f __attribute__((ext_vector_type(2)));

__device__ __forceinline__ float exp2n(float x) { return __builtin_amdgcn_exp2f(x); }
__device__ __forceinline__ float log2n(float x) { return __builtin_amdgcn_logf(x); }

// ---------------------------------------------------------------------------
// R10 comp-packed structure + 2-deep register double-buffer on coef chunks.
// Rationale (R9 ablation + R10 null result): fp32 fma floor is scalar-rate
// (v_pk_fma_f32 = issue-equivalent to 2 scalar fmas on gfx950), so the only
// recoverable time is the 33% VALU-idle from lgkmcnt stalls: each chunk's 6
// ds_read_b128 were consumed immediately. Prefetch chunk k+1 while computing
// chunk k (~112 cyc of fma+exp cover vs ~120 cyc LDS latency).
// Named buffers, static indexing only (rule #20); ~95 VGPR -> 5 waves/SIMD
// capacity >= 3.82 waves of work (R5 lesson: never cap below work level).
// ---------------------------------------------------------------------------
__global__ __launch_bounds__(256) void gm_fused(
    const float* __restrict__ sample, // (N,2)
    const float* __restrict__ mu,     // (64,2)
    const float* __restrict__ A,      // (64,2,2)
    const float* __restrict__ w,      // (64,1)
    float* __restrict__ out)          // (N,1)
{
    __shared__ float cf[6 * M_COMP];

    const int tid = threadIdx.x;
    const float L2E = 1.4426950408889634f;
    const float LN2 = 0.6931471805599453f;

    if (tid < 64) {                       // wave 0: coefficient phase
        const int j = tid;
        const float a00 = A[j*4+0], a01 = A[j*4+1], a10 = A[j*4+2], a11 = A[j*4+3];
        const float g00 = 0.5f*(a00*a00 + a01*a01);
        const float g01 = 0.5f*(a00*a10 + a01*a11);
        const float g11 = 0.5f*(a10*a10 + a11*a11);
        const float det = g00*g11 - g01*g01;

        const float m0 = mu[j*2+0], m1 = mu[j*2+1];
        const float Gmu0 = g00*m0 + g01*m1;
        const float Gmu1 = g01*m0 + g11*m1;
        const float cst  = m0*Gmu0 + m1*Gmu1;

        const float wj = w[j];
        float mx = wj;
        #pragma unroll
        for (int m = 1; m < 64; m <<= 1)
            mx = fmaxf(mx, __shfl_xor(mx, m, 64));
        float se = exp2n((wj - mx) * L2E);
        #pragma unroll
        for (int m = 1; m < 64; m <<= 1)
            se += __shfl_xor(se, m, 64);
        const float lse  = mx + log2n(se) * LN2;
        const float wlog = wj - lse + 0.5f * log2n(det) * LN2;

        cf[0*M_COMP+j] = -g00 * L2E;
        cf[1*M_COMP+j] = -(g01+g01) * L2E;
        cf[2*M_COMP+j] = -g11 * L2E;
        cf[3*M_COMP+j] = (Gmu0+Gmu0) * L2E;
        cf[4*M_COMP+j] = (Gmu1+Gmu1) * L2E;
        cf[5*M_COMP+j] = (wlog - cst) * L2E;
    }
    __syncthreads();

    const int t  = blockIdx.x * 256 + tid;   // 4 points per thread
    const int p0 = t * 4;
    const bool ok = p0 < N_PTS;
    const int  pl = ok ? p0 : 0;             // clamp OOB, keep wave intact

    const float4* s4 = (const float4*)sample;
    const float4 qa = s4[(pl >> 1) + 0];     // points p0, p0+1
    const float4 qb = s4[(pl >> 1) + 1];     // points p0+2, p0+3

    // Per-point values, hoisted (comp-loop-invariant), static unroll only.
    const float x0v[4]  = {qa.x, qa.z, qb.x, qb.z};
    const float x1v[4]  = {qa.y, qa.w, qb.y, qb.w};
    float xx0v[4], x01v[4], xx1v[4];
    #pragma unroll
    for (int p = 0; p < 4; ++p) {
        xx0v[p] = x0v[p]*x0v[p];
        x01v[p] = x0v[p]*x1v[p];
        xx1v[p] = x1v[p]*x1v[p];
    }

    v2f acc[4] = {{0.f,0.f},{0.f,0.f},{0.f,0.f},{0.f,0.f}}; // [point] comp-pair

    // -------- 2-deep pipelined chunk loop: load k+1, compute k ------------
    float4 A0,A1,A2,A3,A4,A5;    // buffer A
    float4 B0,B1,B2,B3,B4,B5;    // buffer B

#define LOADBUF(Z0,Z1,Z2,Z3,Z4,Z5, JC)                    \
    Z0 = *(const float4*)&cf[0*M_COMP+(JC)];              \
    Z1 = *(const float4*)&cf[1*M_COMP+(JC)];              \
    Z2 = *(const float4*)&cf[2*M_COMP+(JC)];              \
    Z3 = *(const float4*)&cf[3*M_COMP+(JC)];              \
    Z4 = *(const float4*)&cf[4*M_COMP+(JC)];              \
    Z5 = *(const float4*)&cf[5*M_COMP+(JC)];

#define COMPUTE(Z0,Z1,Z2,Z3,Z4,Z5)                                          \
    {                                                                       \
        const v2f c0lo = {Z0.x, Z0.y}, c0hi = {Z0.z, Z0.w};                 \
        const v2f c1lo = {Z1.x, Z1.y}, c1hi = {Z1.z, Z1.w};                 \
        const v2f c2lo = {Z2.x, Z2.y}, c2hi = {Z2.z, Z2.w};                 \
        const v2f c3lo = {Z3.x, Z3.y}, c3hi = {Z3.z, Z3.w};                 \
        const v2f c4lo = {Z4.x, Z4.y}, c4hi = {Z4.z, Z4.w};                 \
        const v2f c5lo = {Z5.x, Z5.y}, c5hi = {Z5.z, Z5.w};                 \
        _Pragma("unroll")                                                   \
        for (int p = 0; p < 4; ++p) {                                       \
            const v2f X0  = {x0v[p],  x0v[p]};                              \
            const v2f X1  = {x1v[p],  x1v[p]};                              \
            const v2f XX0 = {xx0v[p], xx0v[p]};                             \
            const v2f X01 = {x01v[p], x01v[p]};                             \
            const v2f XX1 = {xx1v[p], xx1v[p]};                             \
            v2f s = c5lo;                                                   \
            s = __builtin_elementwise_fma(c4lo, X1,  s);                    \
            s = __builtin_elementwise_fma(c3lo, X0,  s);                    \
            s = __builtin_elementwise_fma(c2lo, XX1, s);                    \
            s = __builtin_elementwise_fma(c1lo, X01, s);                    \
            s = __builtin_elementwise_fma(c0lo, XX0, s);                    \
            acc[p][0] += exp2n(s[0]);                                       \
            acc[p][1] += exp2n(s[1]);                                       \
            v2f r = c5hi;                                                   \
            r = __builtin_elementwise_fma(c4hi, X1,  r);                    \
            r = __builtin_elementwise_fma(c3hi, X0,  r);                    \
            r = __builtin_elementwise_fma(c2hi, XX1, r);                    \
            r = __builtin_elementwise_fma(c1hi, X01, r);                    \
            r = __builtin_elementwise_fma(c0hi, XX0, r);                    \
            acc[p][0] += exp2n(r[0]);                                       \
            acc[p][1] += exp2n(r[1]);                                       \
        }                                                                   \
    }

    LOADBUF(A0,A1,A2,A3,A4,A5, 0)
    #pragma unroll 1
    for (int jc = 0; jc < M_COMP - 8; jc += 8) {
        LOADBUF(B0,B1,B2,B3,B4,B5, jc + 4)   // prefetch next chunk
        COMPUTE(A0,A1,A2,A3,A4,A5)           // compute chunk jc
        LOADBUF(A0,A1,A2,A3,A4,A5, jc + 8)   // prefetch chunk jc+8
        COMPUTE(B0,B1,B2,B3,B4,B5)           // compute chunk jc+4
    }
    // tail: A holds chunk 56
    LOADBUF(B0,B1,B2,B3,B4,B5, M_COMP - 4)
    COMPUTE(A0,A1,A2,A3,A4,A5)               // chunk 56
    COMPUTE(B0,B1,B2,B3,B4,B5)               // chunk 60
#undef LOADBUF
#undef COMPUTE

    if (ok) {
        float4 o;                            // horizontal comp-pair merge
        o.x = log2n(acc[0][0] + acc[0][1]) * LN2;
        o.y = log2n(acc[1][0] + acc[1][1]) * LN2;
        o.z = log2n(acc[2][0] + acc[2][1]) * LN2;
        o.w = log2n(acc[3][0] + acc[3][1]) * LN2;
        *(float4*)&out[p0] = o;
    }
}

extern "C" void kernel_launch(void* const* d_in, const int* in_sizes, int n_in,
                              void* d_out, int out_size, void* d_ws, size_t ws_size,
                              hipStream_t stream)
{
    const float* sample = (const float*)d_in[0];  // (1e6, 2) f32
    const float* mu     = (const float*)d_in[1];  // (64, 2)  f32
    const float* A      = (const float*)d_in[2];  // (64,2,2) f32
    const float* w      = (const float*)d_in[3];  // (64, 1)  f32
    float* out = (float*)d_out;                   // (1e6, 1) f32

    const int blocks = (N_PTS/4 + 255) / 256;     // 977
    gm_fused<<<blocks, 256, 0, stream>>>(sample, mu, A, w, out);
}

// Round 12
// 17.521 us; speedup vs baseline: 1.0086x; 1.0086x over previous
//
#include <hip/hip_runtime.h>
#include <math.h>

#define N_PTS  1000000
#define M_COMP 64

typedef float v2f __attribute__((ext_vector_type(2)));

__device__ __forceinline__ float exp2n(float x) { return __builtin_amdgcn_exp2f(x); }
__device__ __forceinline__ float log2n(float x) { return __builtin_amdgcn_logf(x); }

// ---------------------------------------------------------------------------
// Occupancy round. Ledger: plateau ~17.5us survives point-pack/comp-pack/
// SGPR-coef/LDS-dbuf; R9 says VALUBusy=67% with ~13us GPU compute and an
// ~8us 100%-busy issue floor. The untested lever is wave count: 4 pts/thread
// gave only 3.82 waves/SIMD. This kernel: 2 pts/thread -> 1954 blocks ->
// 7.6 waves/SIMD, total VALU work unchanged, dependency/trans latency now
// covered by 2x wave-level parallelism.
// Everything else identical to the R10 comp-packed fused kernel:
//  - wave 0 computes 6 coefs/comp (pre-scaled by log2e) -> LDS SoA cf[k][64]
//  - comp-packed v2f math: coef pairs are register-adjacent float4 halves
//    (zero-cost operands); point values are comp-loop-invariant splats
//  - max-free logsumexp (quadratic form <= 0, wlog ~ 0.5; far comps flush
//    to 0 in fp32 harmlessly), native v_exp_f32 / v_log_f32
// ---------------------------------------------------------------------------
__global__ __launch_bounds__(256) void gm_fused(
    const float* __restrict__ sample, // (N,2)
    const float* __restrict__ mu,     // (64,2)
    const float* __restrict__ A,      // (64,2,2)
    const float* __restrict__ w,      // (64,1)
    float* __restrict__ out)          // (N,1)
{
    __shared__ float cf[6 * M_COMP];

    const int tid = threadIdx.x;
    const float L2E = 1.4426950408889634f;
    const float LN2 = 0.6931471805599453f;

    if (tid < 64) {                       // wave 0: coefficient phase
        const int j = tid;
        const float a00 = A[j*4+0], a01 = A[j*4+1], a10 = A[j*4+2], a11 = A[j*4+3];
        const float g00 = 0.5f*(a00*a00 + a01*a01);
        const float g01 = 0.5f*(a00*a10 + a01*a11);
        const float g11 = 0.5f*(a10*a10 + a11*a11);
        const float det = g00*g11 - g01*g01;

        const float m0 = mu[j*2+0], m1 = mu[j*2+1];
        const float Gmu0 = g00*m0 + g01*m1;
        const float Gmu1 = g01*m0 + g11*m1;
        const float cst  = m0*Gmu0 + m1*Gmu1;

        const float wj = w[j];
        float mx = wj;
        #pragma unroll
        for (int m = 1; m < 64; m <<= 1)
            mx = fmaxf(mx, __shfl_xor(mx, m, 64));
        float se = exp2n((wj - mx) * L2E);
        #pragma unroll
        for (int m = 1; m < 64; m <<= 1)
            se += __shfl_xor(se, m, 64);
        const float lse  = mx + log2n(se) * LN2;
        const float wlog = wj - lse + 0.5f * log2n(det) * LN2;

        cf[0*M_COMP+j] = -g00 * L2E;
        cf[1*M_COMP+j] = -(g01+g01) * L2E;
        cf[2*M_COMP+j] = -g11 * L2E;
        cf[3*M_COMP+j] = (Gmu0+Gmu0) * L2E;
        cf[4*M_COMP+j] = (Gmu1+Gmu1) * L2E;
        cf[5*M_COMP+j] = (wlog - cst) * L2E;
    }
    __syncthreads();

    const int t  = blockIdx.x * 256 + tid;   // 2 points per thread
    const int p0 = t * 2;
    const bool ok = p0 < N_PTS;              // N%2==0
    const int  pl = ok ? p0 : 0;             // clamp OOB, keep wave intact

    const float4 q = ((const float4*)sample)[pl >> 1];  // points p0, p0+1

    // Per-point values, hoisted (comp-loop-invariant), static unroll only.
    const float x0v[2]  = {q.x, q.z};
    const float x1v[2]  = {q.y, q.w};
    float xx0v[2], x01v[2], xx1v[2];
    #pragma unroll
    for (int p = 0; p < 2; ++p) {
        xx0v[p] = x0v[p]*x0v[p];
        x01v[p] = x0v[p]*x1v[p];
        xx1v[p] = x1v[p]*x1v[p];
    }

    v2f acc[2] = {{0.f,0.f},{0.f,0.f}};      // [point] over comp-pair

    #pragma unroll 2
    for (int jc = 0; jc < M_COMP; jc += 4) {
        const float4 c0 = *(const float4*)&cf[0*M_COMP+jc];
        const float4 c1 = *(const float4*)&cf[1*M_COMP+jc];
        const float4 c2 = *(const float4*)&cf[2*M_COMP+jc];
        const float4 c3 = *(const float4*)&cf[3*M_COMP+jc];
        const float4 c4 = *(const float4*)&cf[4*M_COMP+jc];
        const float4 c5 = *(const float4*)&cf[5*M_COMP+jc];

        // zero-cost v2f views of the float4 halves (register-adjacent)
        const v2f c0lo = {c0.x, c0.y}, c0hi = {c0.z, c0.w};
        const v2f c1lo = {c1.x, c1.y}, c1hi = {c1.z, c1.w};
        const v2f c2lo = {c2.x, c2.y}, c2hi = {c2.z, c2.w};
        const v2f c3lo = {c3.x, c3.y}, c3hi = {c3.z, c3.w};
        const v2f c4lo = {c4.x, c4.y}, c4hi = {c4.z, c4.w};
        const v2f c5lo = {c5.x, c5.y}, c5hi = {c5.z, c5.w};

        #pragma unroll
        for (int p = 0; p < 2; ++p) {
            const v2f X0  = {x0v[p],  x0v[p]};   // hoisted across jc loop
            const v2f X1  = {x1v[p],  x1v[p]};
            const v2f XX0 = {xx0v[p], xx0v[p]};
            const v2f X01 = {x01v[p], x01v[p]};
            const v2f XX1 = {xx1v[p], xx1v[p]};

            v2f s = c5lo;                        // comps jc, jc+1
            s = __builtin_elementwise_fma(c4lo, X1,  s);
            s = __builtin_elementwise_fma(c3lo, X0,  s);
            s = __builtin_elementwise_fma(c2lo, XX1, s);
            s = __builtin_elementwise_fma(c1lo, X01, s);
            s = __builtin_elementwise_fma(c0lo, XX0, s);
            acc[p][0] += exp2n(s[0]);
            acc[p][1] += exp2n(s[1]);

            v2f r = c5hi;                        // comps jc+2, jc+3
            r = __builtin_elementwise_fma(c4hi, X1,  r);
            r = __builtin_elementwise_fma(c3hi, X0,  r);
            r = __builtin_elementwise_fma(c2hi, XX1, r);
            r = __builtin_elementwise_fma(c1hi, X01, r);
            r = __builtin_elementwise_fma(c0hi, XX0, r);
            acc[p][0] += exp2n(r[0]);
            acc[p][1] += exp2n(r[1]);
        }
    }

    if (ok) {
        float2 o;                                // horizontal comp-pair merge
        o.x = log2n(acc[0][0] + acc[0][1]) * LN2;
        o.y = log2n(acc[1][0] + acc[1][1]) * LN2;
        *(float2*)&out[p0] = o;
    }
}

extern "C" void kernel_launch(void* const* d_in, const int* in_sizes, int n_in,
                              void* d_out, int out_size, void* d_ws, size_t ws_size,
                              hipStream_t stream)
{
    const float* sample = (const float*)d_in[0];  // (1e6, 2) f32
    const float* mu     = (const float*)d_in[1];  // (64, 2)  f32
    const float* A      = (const float*)d_in[2];  // (64,2,2) f32
    const float* w      = (const float*)d_in[3];  // (64, 1)  f32
    float* out = (float*)d_out;                   // (1e6, 1) f32

    const int blocks = (N_PTS/2 + 255) / 256;     // 1954 -> 7.6 waves/SIMD
    gm_fused<<<blocks, 256, 0, stream>>>(sample, mu, A, w, out);
}